// Round 7
// baseline (1488.254 us; speedup 1.0000x reference)
//
#include <hip/hip_runtime.h>
#include <math.h>

#define CC 256       // channels = HEADS * HD
#define HEADS 4
#define HD 64
#define NG 64        // num graphs
#define SCAN_BS 512
#define QKVS 768     // fused QKV row stride
#define LDK 40       // padded LDS k-stride (bf16 elems)

typedef __attribute__((ext_vector_type(8))) short s16x8;   // 8 x bf16 (4 VGPRs)
typedef __attribute__((ext_vector_type(4))) float f32x4;

static __device__ __forceinline__ float bf2f(unsigned short u) {
  return (float)__builtin_bit_cast(__bf16, u);
}
// non-temporal float4 load (evict-first in L2/LLC: keep LLC for the random K/V gathers)
static __device__ __forceinline__ f32x4 ntld4(const float* p) {
  return __builtin_nontemporal_load((const f32x4*)p);
}

// ---------------- CSR build (by dst) ----------------
__global__ void hist_kernel(const int* __restrict__ dst, int* __restrict__ deg, int E) {
  int e = blockIdx.x * blockDim.x + threadIdx.x;
  if (e < E) atomicAdd(&deg[dst[e]], 1);
}

__global__ void scan1_kernel(const int* __restrict__ deg, int* __restrict__ exc,
                             int* __restrict__ partial, int n) {
  __shared__ int s[SCAN_BS];
  int t = threadIdx.x;
  int g = blockIdx.x * SCAN_BS + t;
  int v = (g < n) ? deg[g] : 0;
  s[t] = v;
  __syncthreads();
  for (int off = 1; off < SCAN_BS; off <<= 1) {
    int add = (t >= off) ? s[t - off] : 0;
    __syncthreads();
    s[t] += add;
    __syncthreads();
  }
  if (g < n) exc[g] = s[t] - v;
  if (t == SCAN_BS - 1) partial[blockIdx.x] = s[t];
}

__global__ void scan2_kernel(int* __restrict__ partial, int nb) {
  __shared__ int s[SCAN_BS];
  int t = threadIdx.x;
  int v = (t < nb) ? partial[t] : 0;
  s[t] = v;
  __syncthreads();
  for (int off = 1; off < SCAN_BS; off <<= 1) {
    int add = (t >= off) ? s[t - off] : 0;
    __syncthreads();
    s[t] += add;
    __syncthreads();
  }
  if (t < nb) partial[t] = s[t] - v;
}

__global__ void scan3_kernel(const int* __restrict__ exc, const int* __restrict__ partial,
                             int* __restrict__ row_start, int* __restrict__ cursor,
                             int n, int E) {
  int g = blockIdx.x * blockDim.x + threadIdx.x;
  if (g < n) {
    int v = exc[g] + partial[g / SCAN_BS];
    row_start[g] = v;
    cursor[g] = v;
  }
  if (g == n) row_start[n] = E;
}

__global__ void scatter_kernel(const int* __restrict__ srcArr, const int* __restrict__ dstArr,
                               int* __restrict__ cursor, int* __restrict__ csr_src,
                               int* __restrict__ csr_dst, int E) {
  int e = blockIdx.x * blockDim.x + threadIdx.x;
  if (e < E) {
    int d = dstArr[e];
    int p = atomicAdd(&cursor[d], 1);
    csr_src[p] = srcArr[e];
    csr_dst[p] = d;
  }
}

// ---------------- weight prep: transpose + concat + bf16 hi/lo split ----------------
__global__ void wprep_kernel(const float* __restrict__ Wq, const float* __restrict__ Wk,
                             const float* __restrict__ Wv, const float* __restrict__ bq,
                             const float* __restrict__ bk, const float* __restrict__ bv,
                             unsigned short* __restrict__ Bth, unsigned short* __restrict__ Btl,
                             float* __restrict__ biascat, int L) {
  int idx = blockIdx.x * 256 + threadIdx.x;
  int total = L * QKVS * CC;
  if (idx >= total) return;
  int k = idx & 255;
  int n = (idx >> 8) % QKVS;
  int l = idx / (QKVS * CC);
  int part = n >> 8;
  int nn = n & 255;
  const float* W = part == 0 ? Wq : (part == 1 ? Wk : Wv);
  float v = W[((long)l * CC + k) * CC + nn];
  __bf16 h = (__bf16)v;
  Bth[idx] = __builtin_bit_cast(unsigned short, h);
  Btl[idx] = __builtin_bit_cast(unsigned short, (__bf16)(v - (float)h));
  if (k == 0) {
    const float* bb = part == 0 ? bq : (part == 1 ? bk : bv);
    biascat[l * QKVS + n] = bb[l * CC + nn];
  }
}

// ---------------- activation split: fp32 -> bf16 hi + lo (layer-0 input only) ------
__global__ void split_kernel(const float* __restrict__ in, unsigned short* __restrict__ hi,
                             unsigned short* __restrict__ lo, int n4) {
  int i = blockIdx.x * 256 + threadIdx.x;
  if (i >= n4) return;
  float4 v = ((const float4*)in)[i];
  __bf16 h0 = (__bf16)v.x, h1 = (__bf16)v.y, h2 = (__bf16)v.z, h3 = (__bf16)v.w;
  ushort4 hv = make_ushort4(__builtin_bit_cast(unsigned short, h0),
                            __builtin_bit_cast(unsigned short, h1),
                            __builtin_bit_cast(unsigned short, h2),
                            __builtin_bit_cast(unsigned short, h3));
  ushort4 lv = make_ushort4(__builtin_bit_cast(unsigned short, (__bf16)(v.x - (float)h0)),
                            __builtin_bit_cast(unsigned short, (__bf16)(v.y - (float)h1)),
                            __builtin_bit_cast(unsigned short, (__bf16)(v.z - (float)h2)),
                            __builtin_bit_cast(unsigned short, (__bf16)(v.w - (float)h3)));
  ((ushort4*)hi)[i] = hv;
  ((ushort4*)lo)[i] = lv;
}

// ---------------- fused QKV GEMM via split-bf16 MFMA ----------------
__global__ __launch_bounds__(256) void qkv_gemm(const unsigned short* __restrict__ Ah,
                                                const unsigned short* __restrict__ Al,
                                                const unsigned short* __restrict__ Bh,
                                                const unsigned short* __restrict__ Bl,
                                                const float* __restrict__ biascat,
                                                float* __restrict__ C, int M) {
  __shared__ unsigned short As_h[128 * LDK], As_l[128 * LDK];
  __shared__ unsigned short Bs_h[128 * LDK], Bs_l[128 * LDK];
  int t = threadIdx.x;
  int bm = blockIdx.x, bn = blockIdx.y;
  int lane = t & 63, wave = t >> 6;
  int mo = (wave >> 1) * 64, no = (wave & 1) * 64;
  int col_l = lane & 15, q = lane >> 4;

  f32x4 acc[4][4];
#pragma unroll
  for (int i = 0; i < 4; ++i)
#pragma unroll
    for (int j = 0; j < 4; ++j) acc[i][j] = (f32x4)0.f;

  int sr = t >> 1;
  int sh = (t & 1) * 16;
  long arow = (long)bm * 128 + sr;
  bool aval = arow < M;
  const unsigned short* agh = Ah + arow * CC + sh;
  const unsigned short* agl = Al + arow * CC + sh;
  const unsigned short* bgh = Bh + ((long)bn * 128 + sr) * CC + sh;
  const unsigned short* bgl = Bl + ((long)bn * 128 + sr) * CC + sh;
  uint4 zz = make_uint4(0, 0, 0, 0);

  for (int kt = 0; kt < CC; kt += 32) {
    uint4 ah0 = zz, ah1 = zz, al0 = zz, al1 = zz;
    if (aval) {
      ah0 = *(const uint4*)(agh + kt);
      ah1 = *(const uint4*)(agh + kt + 8);
      al0 = *(const uint4*)(agl + kt);
      al1 = *(const uint4*)(agl + kt + 8);
    }
    uint4 bh0 = *(const uint4*)(bgh + kt);
    uint4 bh1 = *(const uint4*)(bgh + kt + 8);
    uint4 bl0 = *(const uint4*)(bgl + kt);
    uint4 bl1 = *(const uint4*)(bgl + kt + 8);
    __syncthreads();
    *(uint4*)&As_h[sr * LDK + sh] = ah0;
    *(uint4*)&As_h[sr * LDK + sh + 8] = ah1;
    *(uint4*)&As_l[sr * LDK + sh] = al0;
    *(uint4*)&As_l[sr * LDK + sh + 8] = al1;
    *(uint4*)&Bs_h[sr * LDK + sh] = bh0;
    *(uint4*)&Bs_h[sr * LDK + sh + 8] = bh1;
    *(uint4*)&Bs_l[sr * LDK + sh] = bl0;
    *(uint4*)&Bs_l[sr * LDK + sh + 8] = bl1;
    __syncthreads();

    s16x8 afh[4], afl[4], bfh[4], bfl[4];
#pragma unroll
    for (int i = 0; i < 4; ++i) {
      int am = mo + i * 16 + col_l;
      afh[i] = *(const s16x8*)&As_h[am * LDK + q * 8];
      afl[i] = *(const s16x8*)&As_l[am * LDK + q * 8];
      int bnn = no + i * 16 + col_l;
      bfh[i] = *(const s16x8*)&Bs_h[bnn * LDK + q * 8];
      bfl[i] = *(const s16x8*)&Bs_l[bnn * LDK + q * 8];
    }
#pragma unroll
    for (int i = 0; i < 4; ++i)
#pragma unroll
      for (int j = 0; j < 4; ++j) {
        acc[i][j] = __builtin_amdgcn_mfma_f32_16x16x32_bf16(afh[i], bfh[j], acc[i][j], 0, 0, 0);
        acc[i][j] = __builtin_amdgcn_mfma_f32_16x16x32_bf16(afh[i], bfl[j], acc[i][j], 0, 0, 0);
        acc[i][j] = __builtin_amdgcn_mfma_f32_16x16x32_bf16(afl[i], bfh[j], acc[i][j], 0, 0, 0);
      }
  }

  long rbase = (long)bm * 128 + mo;
  int cbase = bn * 128 + no;
#pragma unroll
  for (int j = 0; j < 4; ++j) {
    int col = cbase + j * 16 + col_l;
    float bias = biascat[col];
#pragma unroll
    for (int i = 0; i < 4; ++i) {
#pragma unroll
      for (int r = 0; r < 4; ++r) {
        long row = rbase + i * 16 + q * 4 + r;
        if (row < M) C[row * QKVS + col] = acc[i][j][r] + bias;
      }
    }
  }
}

// ---------------- attention phase 1: per-edge logits (4 edges/wave, nt streams) ----
__global__ __launch_bounds__(256) void edge_logits_kernel(const float* __restrict__ qkv,
                                                          const int* __restrict__ csr_src,
                                                          const int* __restrict__ csr_dst,
                                                          float* __restrict__ logits, int E) {
  int wave = threadIdx.x >> 6;
  int lane = threadIdx.x & 63;
  int base = blockIdx.x * 16 + wave;
  int e0 = base, e1 = base + 4, e2 = base + 8, e3 = base + 12;
  bool v0 = e0 < E, v1 = e1 < E, v2 = e2 < E, v3 = e3 < E;
  int s0i = v0 ? __builtin_nontemporal_load(csr_src + e0) : 0;
  int s1i = v1 ? __builtin_nontemporal_load(csr_src + e1) : 0;
  int s2i = v2 ? __builtin_nontemporal_load(csr_src + e2) : 0;
  int s3i = v3 ? __builtin_nontemporal_load(csr_src + e3) : 0;
  int d0i = v0 ? __builtin_nontemporal_load(csr_dst + e0) : 0;
  int d1i = v1 ? __builtin_nontemporal_load(csr_dst + e1) : 0;
  int d2i = v2 ? __builtin_nontemporal_load(csr_dst + e2) : 0;
  int d3i = v3 ? __builtin_nontemporal_load(csr_dst + e3) : 0;
  // Q rows: reuse window is only the ~deg consecutive edges of one dst -> nt (evict first).
  // K rows: random gather over 51 MB plane -> keep cached so LLC retains the plane.
  const f32x4 q0 = ntld4(qkv + (size_t)d0i * QKVS + lane * 4);
  const f32x4 k0 = *(const f32x4*)(qkv + (size_t)s0i * QKVS + 256 + lane * 4);
  const f32x4 q1 = ntld4(qkv + (size_t)d1i * QKVS + lane * 4);
  const f32x4 k1 = *(const f32x4*)(qkv + (size_t)s1i * QKVS + 256 + lane * 4);
  const f32x4 q2 = ntld4(qkv + (size_t)d2i * QKVS + lane * 4);
  const f32x4 k2 = *(const f32x4*)(qkv + (size_t)s2i * QKVS + 256 + lane * 4);
  const f32x4 q3 = ntld4(qkv + (size_t)d3i * QKVS + lane * 4);
  const f32x4 k3 = *(const f32x4*)(qkv + (size_t)s3i * QKVS + 256 + lane * 4);
  float dot0 = q0.x * k0.x + q0.y * k0.y + q0.z * k0.z + q0.w * k0.w;
  float dot1 = q1.x * k1.x + q1.y * k1.y + q1.z * k1.z + q1.w * k1.w;
  float dot2 = q2.x * k2.x + q2.y * k2.y + q2.z * k2.z + q2.w * k2.w;
  float dot3 = q3.x * k3.x + q3.y * k3.y + q3.z * k3.z + q3.w * k3.w;
#pragma unroll
  for (int off = 1; off < 16; off <<= 1) {
    dot0 += __shfl_xor(dot0, off, 64);
    dot1 += __shfl_xor(dot1, off, 64);
    dot2 += __shfl_xor(dot2, off, 64);
    dot3 += __shfl_xor(dot3, off, 64);
  }
  if ((lane & 15) == 0) {
    int h = lane >> 4;
    float* plane = logits + (size_t)h * E;
    if (v0) __builtin_nontemporal_store(dot0 * 0.125f, plane + e0);
    if (v1) __builtin_nontemporal_store(dot1 * 0.125f, plane + e1);
    if (v2) __builtin_nontemporal_store(dot2 * 0.125f, plane + e2);
    if (v3) __builtin_nontemporal_store(dot3 * 0.125f, plane + e3);
  }
}

// ---------------- attention phase 2+3 fused: softmax + V aggregation + ReLU -------
// block = node, wave = head. Wave first computes (m, 1/z) over its logits segment
// with lane-parallel coalesced reads, then runs the 8x-unrolled V gather.
__global__ __launch_bounds__(256) void aggregate_kernel(const float* __restrict__ qkv,
                                                        const float* __restrict__ logits,
                                                        const int* __restrict__ row_start,
                                                        const int* __restrict__ csr_src,
                                                        unsigned short* __restrict__ h_hi,
                                                        unsigned short* __restrict__ h_lo,
                                                        int N, int E) {
  int node = blockIdx.x;
  int wave = threadIdx.x >> 6;
  int lane = threadIdx.x & 63;
  int s0 = row_start[node], s1 = row_start[node + 1];
  float h = 0.f;
  if (s1 > s0) {
    const float* lp = logits + (size_t)wave * E;
    // lane-parallel max
    float m = -1e30f;
    for (int i = s0 + lane; i < s1; i += 64) m = fmaxf(m, lp[i]);
#pragma unroll
    for (int off = 32; off; off >>= 1) m = fmaxf(m, __shfl_xor(m, off, 64));
    // lane-parallel exp-sum
    float z = 0.f;
    for (int i = s0 + lane; i < s1; i += 64) z += __expf(lp[i] - m);
#pragma unroll
    for (int off = 32; off; off >>= 1) z += __shfl_xor(z, off, 64);
    float rz = 1.f / (z + 1e-16f);

    const float* vbase = qkv + 512 + threadIdx.x;
    float acc = 0.f;
    int i = s0;
    for (; i + 8 <= s1; i += 8) {
      int ix[8];
      float lg[8], vv[8];
#pragma unroll
      for (int u = 0; u < 8; ++u) ix[u] = csr_src[i + u];
#pragma unroll
      for (int u = 0; u < 8; ++u) lg[u] = lp[i + u];
#pragma unroll
      for (int u = 0; u < 8; ++u) vv[u] = vbase[(size_t)ix[u] * QKVS];
#pragma unroll
      for (int u = 0; u < 8; ++u) acc = fmaf(__expf(lg[u] - m) * rz, vv[u], acc);
    }
    for (; i + 4 <= s1; i += 4) {
      int a = csr_src[i], b = csr_src[i + 1], c = csr_src[i + 2], d = csr_src[i + 3];
      float la = lp[i], lb = lp[i + 1], lc = lp[i + 2], ld = lp[i + 3];
      float va = vbase[(size_t)a * QKVS];
      float vb = vbase[(size_t)b * QKVS];
      float vc = vbase[(size_t)c * QKVS];
      float vd = vbase[(size_t)d * QKVS];
      acc = fmaf(__expf(la - m) * rz, va, acc);
      acc = fmaf(__expf(lb - m) * rz, vb, acc);
      acc = fmaf(__expf(lc - m) * rz, vc, acc);
      acc = fmaf(__expf(ld - m) * rz, vd, acc);
    }
    for (; i < s1; ++i) {
      int a = csr_src[i];
      acc = fmaf(__expf(lp[i] - m) * rz, vbase[(size_t)a * QKVS], acc);
    }
    h = fmaxf(acc, 0.f);
  }
  __bf16 hi = (__bf16)h;
  size_t idx = (size_t)node * CC + threadIdx.x;
  __builtin_nontemporal_store(__builtin_bit_cast(unsigned short, hi), h_hi + idx);
  __builtin_nontemporal_store(
      __builtin_bit_cast(unsigned short, (__bf16)(h - (float)hi)), h_lo + idx);
}

// ---------------- pool: parallel segment-sum with atomics (batch sorted) ----------------
__global__ void pool_kernel(const unsigned short* __restrict__ h_hi,
                            const unsigned short* __restrict__ h_lo,
                            const int* __restrict__ batch,
                            float* __restrict__ gpool, int N) {
  int c = threadIdx.x;
  int n0 = blockIdx.x * 64;
  int n1 = min(n0 + 64, N);
  int cur = batch[n0];
  float acc = 0.f;
  for (int n = n0; n < n1; ++n) {
    int g = batch[n];
    if (g != cur) {
      atomicAdd(&gpool[cur * CC + c], acc);
      acc = 0.f;
      cur = g;
    }
    size_t idx = (size_t)n * CC + c;
    acc += bf2f(h_hi[idx]) + bf2f(h_lo[idx]);
  }
  atomicAdd(&gpool[cur * CC + c], acc);
}

// ---------------- MLP head ----------------
__global__ void head_kernel(const float* __restrict__ gpool, const float* __restrict__ W1,
                            const float* __restrict__ b1, const float* __restrict__ W2,
                            const float* __restrict__ b2, float* __restrict__ out) {
  __shared__ float hid[64];
  int g = blockIdx.x, t = threadIdx.x;
  float acc = b1[t];
  for (int i = 0; i < CC; ++i) acc = fmaf(gpool[g * CC + i], W1[i * 64 + t], acc);
  hid[t] = fmaxf(acc, 0.f);
  __syncthreads();
  if (t < 16) {
    float o = b2[t];
    for (int i = 0; i < 64; ++i) o = fmaf(hid[i], W2[i * 16 + t], o);
    out[g * 16 + t] = o;
  }
}

extern "C" void kernel_launch(void* const* d_in, const int* in_sizes, int n_in,
                              void* d_out, int out_size, void* d_ws, size_t ws_size,
                              hipStream_t stream) {
  const float* x  = (const float*)d_in[0];
  const int* ei   = (const int*)d_in[1];
  const int* batch = (const int*)d_in[2];
  const float* Wq = (const float*)d_in[3];
  const float* bq = (const float*)d_in[4];
  const float* Wk = (const float*)d_in[5];
  const float* bk = (const float*)d_in[6];
  const float* Wv = (const float*)d_in[7];
  const float* bv = (const float*)d_in[8];
  const float* W1 = (const float*)d_in[9];
  const float* b1 = (const float*)d_in[10];
  const float* W2 = (const float*)d_in[11];
  const float* b2 = (const float*)d_in[12];
  float* out = (float*)d_out;

  int N = in_sizes[0] / CC;
  int E = in_sizes[1] / 2;
  int L = in_sizes[3] / (CC * CC);
  const int* src = ei;
  const int* dst = ei + E;

  // workspace budget: keep total < 256 MB (R3 crashed at ~278 MB)
  size_t off = 0;
  auto alloc = [&](size_t bytes) -> void* {
    void* p = (char*)d_ws + off;
    off += (bytes + 255) & ~(size_t)255;
    return p;
  };
  float* qkv = (float*)alloc((size_t)N * QKVS * 4);                   // 153.6 MB
  unsigned short* h_hi = (unsigned short*)alloc((size_t)N * CC * 2);  // 25.6 MB
  unsigned short* h_lo = (unsigned short*)alloc((size_t)N * CC * 2);  // 25.6 MB
  unsigned short* Bth = (unsigned short*)alloc((size_t)L * QKVS * CC * 2);
  unsigned short* Btl = (unsigned short*)alloc((size_t)L * QKVS * CC * 2);
  float* biascat = (float*)alloc((size_t)L * QKVS * 4);
  int* deg = (int*)alloc((size_t)N * 4);
  int* exc = (int*)alloc((size_t)N * 4);
  int* partial = (int*)alloc(SCAN_BS * 4);
  int* row_start = (int*)alloc((size_t)(N + 1) * 4);
  int* cursor = (int*)alloc((size_t)N * 4);
  int* csr_src = (int*)alloc((size_t)E * 4);
  int* csr_dst = (int*)alloc((size_t)E * 4);
  float* wbuf = (float*)alloc((size_t)E * HEADS * 4);                 // 12.8 MB
  float* gpool = (float*)alloc((size_t)NG * CC * 4);
  // total ~= 227 MB

  // CSR by dst
  hipMemsetAsync(deg, 0, (size_t)N * 4, stream);
  int eb = (E + 255) / 256;
  hist_kernel<<<eb, 256, 0, stream>>>(dst, deg, E);
  int nb = (N + SCAN_BS - 1) / SCAN_BS;
  scan1_kernel<<<nb, SCAN_BS, 0, stream>>>(deg, exc, partial, N);
  scan2_kernel<<<1, SCAN_BS, 0, stream>>>(partial, nb);
  scan3_kernel<<<(N + 1 + 255) / 256, 256, 0, stream>>>(exc, partial, row_start, cursor, N, E);
  scatter_kernel<<<eb, 256, 0, stream>>>(src, dst, cursor, csr_src, csr_dst, E);

  // weight prep (transpose + concat + hi/lo split)
  int wtot = L * QKVS * CC;
  wprep_kernel<<<(wtot + 255) / 256, 256, 0, stream>>>(Wq, Wk, Wv, bq, bk, bv,
                                                       Bth, Btl, biascat, L);

  // layer-0 input split
  int n4 = N * CC / 4;
  split_kernel<<<(n4 + 255) / 256, 256, 0, stream>>>(x, h_hi, h_lo, n4);

  // layers
  dim3 gemmGrid((N + 127) / 128, QKVS / 128);
  int ewb = (E + 15) / 16;
  for (int l = 0; l < L; ++l) {
    qkv_gemm<<<gemmGrid, 256, 0, stream>>>(h_hi, h_lo,
                                           Bth + (size_t)l * QKVS * CC,
                                           Btl + (size_t)l * QKVS * CC,
                                           biascat + (size_t)l * QKVS, qkv, N);
    edge_logits_kernel<<<ewb, 256, 0, stream>>>(qkv, csr_src, csr_dst, wbuf, E);
    aggregate_kernel<<<N, 256, 0, stream>>>(qkv, wbuf, row_start, csr_src,
                                            h_hi, h_lo, N, E);
  }

  // pool + head
  hipMemsetAsync(gpool, 0, (size_t)NG * CC * 4, stream);
  pool_kernel<<<(N + 63) / 64, 256, 0, stream>>>(h_hi, h_lo, batch, gpool, N);
  head_kernel<<<NG, 64, 0, stream>>>(gpool, W1, b1, W2, b2, out);
}

// Round 8
// 1322.271 us; speedup vs baseline: 1.1255x; 1.1255x over previous
//
#include <hip/hip_runtime.h>
#include <math.h>

#define CC 256       // channels = HEADS * HD
#define HEADS 4
#define HD 64
#define NG 64        // num graphs
#define SCAN_BS 512
#define QKVS 768     // fused QKV row stride
#define LDK 40       // padded LDS k-stride (bf16 elems)

typedef __attribute__((ext_vector_type(8))) short s16x8;   // 8 x bf16 (4 VGPRs)
typedef __attribute__((ext_vector_type(4))) float f32x4;

static __device__ __forceinline__ float bf2f(unsigned short u) {
  return (float)__builtin_bit_cast(__bf16, u);
}

// ---------------- CSR build (by dst) ----------------
__global__ void hist_kernel(const int* __restrict__ dst, int* __restrict__ deg, int E) {
  int e = blockIdx.x * blockDim.x + threadIdx.x;
  if (e < E) atomicAdd(&deg[dst[e]], 1);
}

__global__ void scan1_kernel(const int* __restrict__ deg, int* __restrict__ exc,
                             int* __restrict__ partial, int n) {
  __shared__ int s[SCAN_BS];
  int t = threadIdx.x;
  int g = blockIdx.x * SCAN_BS + t;
  int v = (g < n) ? deg[g] : 0;
  s[t] = v;
  __syncthreads();
  for (int off = 1; off < SCAN_BS; off <<= 1) {
    int add = (t >= off) ? s[t - off] : 0;
    __syncthreads();
    s[t] += add;
    __syncthreads();
  }
  if (g < n) exc[g] = s[t] - v;
  if (t == SCAN_BS - 1) partial[blockIdx.x] = s[t];
}

__global__ void scan2_kernel(int* __restrict__ partial, int nb) {
  __shared__ int s[SCAN_BS];
  int t = threadIdx.x;
  int v = (t < nb) ? partial[t] : 0;
  s[t] = v;
  __syncthreads();
  for (int off = 1; off < SCAN_BS; off <<= 1) {
    int add = (t >= off) ? s[t - off] : 0;
    __syncthreads();
    s[t] += add;
    __syncthreads();
  }
  if (t < nb) partial[t] = s[t] - v;
}

__global__ void scan3_kernel(const int* __restrict__ exc, const int* __restrict__ partial,
                             int* __restrict__ row_start, int* __restrict__ cursor,
                             int n, int E) {
  int g = blockIdx.x * blockDim.x + threadIdx.x;
  if (g < n) {
    int v = exc[g] + partial[g / SCAN_BS];
    row_start[g] = v;
    cursor[g] = v;
  }
  if (g == n) row_start[n] = E;
}

__global__ void scatter_kernel(const int* __restrict__ srcArr, const int* __restrict__ dstArr,
                               int* __restrict__ cursor, int* __restrict__ csr_src,
                               int* __restrict__ csr_dst, int E) {
  int e = blockIdx.x * blockDim.x + threadIdx.x;
  if (e < E) {
    int d = dstArr[e];
    int p = atomicAdd(&cursor[d], 1);
    csr_src[p] = srcArr[e];
    csr_dst[p] = d;
  }
}

// ---------------- weight prep: transpose + concat + bf16 hi/lo split ----------------
__global__ void wprep_kernel(const float* __restrict__ Wq, const float* __restrict__ Wk,
                             const float* __restrict__ Wv, const float* __restrict__ bq,
                             const float* __restrict__ bk, const float* __restrict__ bv,
                             unsigned short* __restrict__ Bth, unsigned short* __restrict__ Btl,
                             float* __restrict__ biascat, int L) {
  int idx = blockIdx.x * 256 + threadIdx.x;
  int total = L * QKVS * CC;
  if (idx >= total) return;
  int k = idx & 255;
  int n = (idx >> 8) % QKVS;
  int l = idx / (QKVS * CC);
  int part = n >> 8;
  int nn = n & 255;
  const float* W = part == 0 ? Wq : (part == 1 ? Wk : Wv);
  float v = W[((long)l * CC + k) * CC + nn];
  __bf16 h = (__bf16)v;
  Bth[idx] = __builtin_bit_cast(unsigned short, h);
  Btl[idx] = __builtin_bit_cast(unsigned short, (__bf16)(v - (float)h));
  if (k == 0) {
    const float* bb = part == 0 ? bq : (part == 1 ? bk : bv);
    biascat[l * QKVS + n] = bb[l * CC + nn];
  }
}

// ---------------- activation split: fp32 -> bf16 hi + lo (layer-0 input only) ------
__global__ void split_kernel(const float* __restrict__ in, unsigned short* __restrict__ hi,
                             unsigned short* __restrict__ lo, int n4) {
  int i = blockIdx.x * 256 + threadIdx.x;
  if (i >= n4) return;
  float4 v = ((const float4*)in)[i];
  __bf16 h0 = (__bf16)v.x, h1 = (__bf16)v.y, h2 = (__bf16)v.z, h3 = (__bf16)v.w;
  ushort4 hv = make_ushort4(__builtin_bit_cast(unsigned short, h0),
                            __builtin_bit_cast(unsigned short, h1),
                            __builtin_bit_cast(unsigned short, h2),
                            __builtin_bit_cast(unsigned short, h3));
  ushort4 lv = make_ushort4(__builtin_bit_cast(unsigned short, (__bf16)(v.x - (float)h0)),
                            __builtin_bit_cast(unsigned short, (__bf16)(v.y - (float)h1)),
                            __builtin_bit_cast(unsigned short, (__bf16)(v.z - (float)h2)),
                            __builtin_bit_cast(unsigned short, (__bf16)(v.w - (float)h3)));
  ((ushort4*)hi)[i] = hv;
  ((ushort4*)lo)[i] = lv;
}

// ---------------- fused QKV GEMM via split-bf16 MFMA ----------------
__global__ __launch_bounds__(256) void qkv_gemm(const unsigned short* __restrict__ Ah,
                                                const unsigned short* __restrict__ Al,
                                                const unsigned short* __restrict__ Bh,
                                                const unsigned short* __restrict__ Bl,
                                                const float* __restrict__ biascat,
                                                float* __restrict__ C, int M) {
  __shared__ unsigned short As_h[128 * LDK], As_l[128 * LDK];
  __shared__ unsigned short Bs_h[128 * LDK], Bs_l[128 * LDK];
  int t = threadIdx.x;
  int bm = blockIdx.x, bn = blockIdx.y;
  int lane = t & 63, wave = t >> 6;
  int mo = (wave >> 1) * 64, no = (wave & 1) * 64;
  int col_l = lane & 15, q = lane >> 4;

  f32x4 acc[4][4];
#pragma unroll
  for (int i = 0; i < 4; ++i)
#pragma unroll
    for (int j = 0; j < 4; ++j) acc[i][j] = (f32x4)0.f;

  int sr = t >> 1;
  int sh = (t & 1) * 16;
  long arow = (long)bm * 128 + sr;
  bool aval = arow < M;
  const unsigned short* agh = Ah + arow * CC + sh;
  const unsigned short* agl = Al + arow * CC + sh;
  const unsigned short* bgh = Bh + ((long)bn * 128 + sr) * CC + sh;
  const unsigned short* bgl = Bl + ((long)bn * 128 + sr) * CC + sh;
  uint4 zz = make_uint4(0, 0, 0, 0);

  for (int kt = 0; kt < CC; kt += 32) {
    uint4 ah0 = zz, ah1 = zz, al0 = zz, al1 = zz;
    if (aval) {
      ah0 = *(const uint4*)(agh + kt);
      ah1 = *(const uint4*)(agh + kt + 8);
      al0 = *(const uint4*)(agl + kt);
      al1 = *(const uint4*)(agl + kt + 8);
    }
    uint4 bh0 = *(const uint4*)(bgh + kt);
    uint4 bh1 = *(const uint4*)(bgh + kt + 8);
    uint4 bl0 = *(const uint4*)(bgl + kt);
    uint4 bl1 = *(const uint4*)(bgl + kt + 8);
    __syncthreads();
    *(uint4*)&As_h[sr * LDK + sh] = ah0;
    *(uint4*)&As_h[sr * LDK + sh + 8] = ah1;
    *(uint4*)&As_l[sr * LDK + sh] = al0;
    *(uint4*)&As_l[sr * LDK + sh + 8] = al1;
    *(uint4*)&Bs_h[sr * LDK + sh] = bh0;
    *(uint4*)&Bs_h[sr * LDK + sh + 8] = bh1;
    *(uint4*)&Bs_l[sr * LDK + sh] = bl0;
    *(uint4*)&Bs_l[sr * LDK + sh + 8] = bl1;
    __syncthreads();

    s16x8 afh[4], afl[4], bfh[4], bfl[4];
#pragma unroll
    for (int i = 0; i < 4; ++i) {
      int am = mo + i * 16 + col_l;
      afh[i] = *(const s16x8*)&As_h[am * LDK + q * 8];
      afl[i] = *(const s16x8*)&As_l[am * LDK + q * 8];
      int bnn = no + i * 16 + col_l;
      bfh[i] = *(const s16x8*)&Bs_h[bnn * LDK + q * 8];
      bfl[i] = *(const s16x8*)&Bs_l[bnn * LDK + q * 8];
    }
#pragma unroll
    for (int i = 0; i < 4; ++i)
#pragma unroll
      for (int j = 0; j < 4; ++j) {
        acc[i][j] = __builtin_amdgcn_mfma_f32_16x16x32_bf16(afh[i], bfh[j], acc[i][j], 0, 0, 0);
        acc[i][j] = __builtin_amdgcn_mfma_f32_16x16x32_bf16(afh[i], bfl[j], acc[i][j], 0, 0, 0);
        acc[i][j] = __builtin_amdgcn_mfma_f32_16x16x32_bf16(afl[i], bfh[j], acc[i][j], 0, 0, 0);
      }
  }

  long rbase = (long)bm * 128 + mo;
  int cbase = bn * 128 + no;
#pragma unroll
  for (int j = 0; j < 4; ++j) {
    int col = cbase + j * 16 + col_l;
    float bias = biascat[col];
#pragma unroll
    for (int i = 0; i < 4; ++i) {
#pragma unroll
      for (int r = 0; r < 4; ++r) {
        long row = rbase + i * 16 + q * 4 + r;
        if (row < M) C[row * QKVS + col] = acc[i][j][r] + bias;
      }
    }
  }
}

// ---------------- attention phase 1: per-edge logits (4 edges/wave; plain loads —
// nt hints regressed in R7: Q rows are L1/L2-hot across ~deg consecutive edges) ----
__global__ __launch_bounds__(256) void edge_logits_kernel(const float* __restrict__ qkv,
                                                          const int* __restrict__ csr_src,
                                                          const int* __restrict__ csr_dst,
                                                          float* __restrict__ logits, int E) {
  int wave = threadIdx.x >> 6;
  int lane = threadIdx.x & 63;
  int base = blockIdx.x * 16 + wave;
  int e0 = base, e1 = base + 4, e2 = base + 8, e3 = base + 12;
  bool v0 = e0 < E, v1 = e1 < E, v2 = e2 < E, v3 = e3 < E;
  int s0i = v0 ? csr_src[e0] : 0;
  int s1i = v1 ? csr_src[e1] : 0;
  int s2i = v2 ? csr_src[e2] : 0;
  int s3i = v3 ? csr_src[e3] : 0;
  int d0i = v0 ? csr_dst[e0] : 0;
  int d1i = v1 ? csr_dst[e1] : 0;
  int d2i = v2 ? csr_dst[e2] : 0;
  int d3i = v3 ? csr_dst[e3] : 0;
  // 8 independent 1KB-row loads in flight; lane*4 covers the full row
  const float4 q0 = *(const float4*)(qkv + (size_t)d0i * QKVS + lane * 4);
  const float4 k0 = *(const float4*)(qkv + (size_t)s0i * QKVS + 256 + lane * 4);
  const float4 q1 = *(const float4*)(qkv + (size_t)d1i * QKVS + lane * 4);
  const float4 k1 = *(const float4*)(qkv + (size_t)s1i * QKVS + 256 + lane * 4);
  const float4 q2 = *(const float4*)(qkv + (size_t)d2i * QKVS + lane * 4);
  const float4 k2 = *(const float4*)(qkv + (size_t)s2i * QKVS + 256 + lane * 4);
  const float4 q3 = *(const float4*)(qkv + (size_t)d3i * QKVS + lane * 4);
  const float4 k3 = *(const float4*)(qkv + (size_t)s3i * QKVS + 256 + lane * 4);
  float dot0 = q0.x * k0.x + q0.y * k0.y + q0.z * k0.z + q0.w * k0.w;
  float dot1 = q1.x * k1.x + q1.y * k1.y + q1.z * k1.z + q1.w * k1.w;
  float dot2 = q2.x * k2.x + q2.y * k2.y + q2.z * k2.z + q2.w * k2.w;
  float dot3 = q3.x * k3.x + q3.y * k3.y + q3.z * k3.z + q3.w * k3.w;
#pragma unroll
  for (int off = 1; off < 16; off <<= 1) {
    dot0 += __shfl_xor(dot0, off, 64);
    dot1 += __shfl_xor(dot1, off, 64);
    dot2 += __shfl_xor(dot2, off, 64);
    dot3 += __shfl_xor(dot3, off, 64);
  }
  if ((lane & 15) == 0) {
    int h = lane >> 4;
    float* plane = logits + (size_t)h * E;
    if (v0) plane[e0] = dot0 * 0.125f;
    if (v1) plane[e1] = dot1 * 0.125f;
    if (v2) plane[e2] = dot2 * 0.125f;
    if (v3) plane[e3] = dot3 * 0.125f;
  }
}

// ---------------- attention phase 2+3 fused: softmax + V aggregation + ReLU -------
// block = node, wave = head. Wave computes (m, 1/z) over its logits segment with
// lane-parallel coalesced reads, then runs the 8x-unrolled V gather.
__global__ __launch_bounds__(256) void aggregate_kernel(const float* __restrict__ qkv,
                                                        const float* __restrict__ logits,
                                                        const int* __restrict__ row_start,
                                                        const int* __restrict__ csr_src,
                                                        unsigned short* __restrict__ h_hi,
                                                        unsigned short* __restrict__ h_lo,
                                                        int N, int E) {
  int node = blockIdx.x;
  int wave = threadIdx.x >> 6;
  int lane = threadIdx.x & 63;
  int s0 = row_start[node], s1 = row_start[node + 1];
  float h = 0.f;
  if (s1 > s0) {
    const float* lp = logits + (size_t)wave * E;
    // lane-parallel max
    float m = -1e30f;
    for (int i = s0 + lane; i < s1; i += 64) m = fmaxf(m, lp[i]);
#pragma unroll
    for (int off = 32; off; off >>= 1) m = fmaxf(m, __shfl_xor(m, off, 64));
    // lane-parallel exp-sum
    float z = 0.f;
    for (int i = s0 + lane; i < s1; i += 64) z += __expf(lp[i] - m);
#pragma unroll
    for (int off = 32; off; off >>= 1) z += __shfl_xor(z, off, 64);
    float rz = 1.f / (z + 1e-16f);

    const float* vbase = qkv + 512 + threadIdx.x;
    float acc = 0.f;
    int i = s0;
    for (; i + 8 <= s1; i += 8) {
      int ix[8];
      float lg[8], vv[8];
#pragma unroll
      for (int u = 0; u < 8; ++u) ix[u] = csr_src[i + u];
#pragma unroll
      for (int u = 0; u < 8; ++u) lg[u] = lp[i + u];
#pragma unroll
      for (int u = 0; u < 8; ++u) vv[u] = vbase[(size_t)ix[u] * QKVS];
#pragma unroll
      for (int u = 0; u < 8; ++u) acc = fmaf(__expf(lg[u] - m) * rz, vv[u], acc);
    }
    for (; i + 4 <= s1; i += 4) {
      int a = csr_src[i], b = csr_src[i + 1], c = csr_src[i + 2], d = csr_src[i + 3];
      float la = lp[i], lb = lp[i + 1], lc = lp[i + 2], ld = lp[i + 3];
      float va = vbase[(size_t)a * QKVS];
      float vb = vbase[(size_t)b * QKVS];
      float vc = vbase[(size_t)c * QKVS];
      float vd = vbase[(size_t)d * QKVS];
      acc = fmaf(__expf(la - m) * rz, va, acc);
      acc = fmaf(__expf(lb - m) * rz, vb, acc);
      acc = fmaf(__expf(lc - m) * rz, vc, acc);
      acc = fmaf(__expf(ld - m) * rz, vd, acc);
    }
    for (; i < s1; ++i) {
      int a = csr_src[i];
      acc = fmaf(__expf(lp[i] - m) * rz, vbase[(size_t)a * QKVS], acc);
    }
    h = fmaxf(acc, 0.f);
  }
  __bf16 hi = (__bf16)h;
  size_t idx = (size_t)node * CC + threadIdx.x;
  h_hi[idx] = __builtin_bit_cast(unsigned short, hi);
  h_lo[idx] = __builtin_bit_cast(unsigned short, (__bf16)(h - (float)hi));
}

// ---------------- pool: parallel segment-sum with atomics (batch sorted) ----------------
__global__ void pool_kernel(const unsigned short* __restrict__ h_hi,
                            const unsigned short* __restrict__ h_lo,
                            const int* __restrict__ batch,
                            float* __restrict__ gpool, int N) {
  int c = threadIdx.x;
  int n0 = blockIdx.x * 64;
  int n1 = min(n0 + 64, N);
  int cur = batch[n0];
  float acc = 0.f;
  for (int n = n0; n < n1; ++n) {
    int g = batch[n];
    if (g != cur) {
      atomicAdd(&gpool[cur * CC + c], acc);
      acc = 0.f;
      cur = g;
    }
    size_t idx = (size_t)n * CC + c;
    acc += bf2f(h_hi[idx]) + bf2f(h_lo[idx]);
  }
  atomicAdd(&gpool[cur * CC + c], acc);
}

// ---------------- MLP head ----------------
__global__ void head_kernel(const float* __restrict__ gpool, const float* __restrict__ W1,
                            const float* __restrict__ b1, const float* __restrict__ W2,
                            const float* __restrict__ b2, float* __restrict__ out) {
  __shared__ float hid[64];
  int g = blockIdx.x, t = threadIdx.x;
  float acc = b1[t];
  for (int i = 0; i < CC; ++i) acc = fmaf(gpool[g * CC + i], W1[i * 64 + t], acc);
  hid[t] = fmaxf(acc, 0.f);
  __syncthreads();
  if (t < 16) {
    float o = b2[t];
    for (int i = 0; i < 64; ++i) o = fmaf(hid[i], W2[i * 16 + t], o);
    out[g * 16 + t] = o;
  }
}

extern "C" void kernel_launch(void* const* d_in, const int* in_sizes, int n_in,
                              void* d_out, int out_size, void* d_ws, size_t ws_size,
                              hipStream_t stream) {
  const float* x  = (const float*)d_in[0];
  const int* ei   = (const int*)d_in[1];
  const int* batch = (const int*)d_in[2];
  const float* Wq = (const float*)d_in[3];
  const float* bq = (const float*)d_in[4];
  const float* Wk = (const float*)d_in[5];
  const float* bk = (const float*)d_in[6];
  const float* Wv = (const float*)d_in[7];
  const float* bv = (const float*)d_in[8];
  const float* W1 = (const float*)d_in[9];
  const float* b1 = (const float*)d_in[10];
  const float* W2 = (const float*)d_in[11];
  const float* b2 = (const float*)d_in[12];
  float* out = (float*)d_out;

  int N = in_sizes[0] / CC;
  int E = in_sizes[1] / 2;
  int L = in_sizes[3] / (CC * CC);
  const int* src = ei;
  const int* dst = ei + E;

  // workspace budget: keep total < 256 MB (R3 crashed at ~278 MB)
  size_t off = 0;
  auto alloc = [&](size_t bytes) -> void* {
    void* p = (char*)d_ws + off;
    off += (bytes + 255) & ~(size_t)255;
    return p;
  };
  float* qkv = (float*)alloc((size_t)N * QKVS * 4);                   // 153.6 MB
  unsigned short* h_hi = (unsigned short*)alloc((size_t)N * CC * 2);  // 25.6 MB
  unsigned short* h_lo = (unsigned short*)alloc((size_t)N * CC * 2);  // 25.6 MB
  unsigned short* Bth = (unsigned short*)alloc((size_t)L * QKVS * CC * 2);
  unsigned short* Btl = (unsigned short*)alloc((size_t)L * QKVS * CC * 2);
  float* biascat = (float*)alloc((size_t)L * QKVS * 4);
  int* deg = (int*)alloc((size_t)N * 4);
  int* exc = (int*)alloc((size_t)N * 4);
  int* partial = (int*)alloc(SCAN_BS * 4);
  int* row_start = (int*)alloc((size_t)(N + 1) * 4);
  int* cursor = (int*)alloc((size_t)N * 4);
  int* csr_src = (int*)alloc((size_t)E * 4);
  int* csr_dst = (int*)alloc((size_t)E * 4);
  float* wbuf = (float*)alloc((size_t)E * HEADS * 4);                 // 12.8 MB
  float* gpool = (float*)alloc((size_t)NG * CC * 4);
  // total ~= 227 MB

  // CSR by dst
  hipMemsetAsync(deg, 0, (size_t)N * 4, stream);
  int eb = (E + 255) / 256;
  hist_kernel<<<eb, 256, 0, stream>>>(dst, deg, E);
  int nb = (N + SCAN_BS - 1) / SCAN_BS;
  scan1_kernel<<<nb, SCAN_BS, 0, stream>>>(deg, exc, partial, N);
  scan2_kernel<<<1, SCAN_BS, 0, stream>>>(partial, nb);
  scan3_kernel<<<(N + 1 + 255) / 256, 256, 0, stream>>>(exc, partial, row_start, cursor, N, E);
  scatter_kernel<<<eb, 256, 0, stream>>>(src, dst, cursor, csr_src, csr_dst, E);

  // weight prep (transpose + concat + hi/lo split)
  int wtot = L * QKVS * CC;
  wprep_kernel<<<(wtot + 255) / 256, 256, 0, stream>>>(Wq, Wk, Wv, bq, bk, bv,
                                                       Bth, Btl, biascat, L);

  // layer-0 input split
  int n4 = N * CC / 4;
  split_kernel<<<(n4 + 255) / 256, 256, 0, stream>>>(x, h_hi, h_lo, n4);

  // layers
  dim3 gemmGrid((N + 127) / 128, QKVS / 128);
  int ewb = (E + 15) / 16;
  for (int l = 0; l < L; ++l) {
    qkv_gemm<<<gemmGrid, 256, 0, stream>>>(h_hi, h_lo,
                                           Bth + (size_t)l * QKVS * CC,
                                           Btl + (size_t)l * QKVS * CC,
                                           biascat + (size_t)l * QKVS, qkv, N);
    edge_logits_kernel<<<ewb, 256, 0, stream>>>(qkv, csr_src, csr_dst, wbuf, E);
    aggregate_kernel<<<N, 256, 0, stream>>>(qkv, wbuf, row_start, csr_src,
                                            h_hi, h_lo, N, E);
  }

  // pool + head
  hipMemsetAsync(gpool, 0, (size_t)NG * CC * 4, stream);
  pool_kernel<<<(N + 63) / 64, 256, 0, stream>>>(h_hi, h_lo, batch, gpool, N);
  head_kernel<<<NG, 64, 0, stream>>>(gpool, W1, b1, W2, b2, out);
}

// Round 9
// 1293.844 us; speedup vs baseline: 1.1503x; 1.0220x over previous
//
#include <hip/hip_runtime.h>
#include <math.h>

#define CC 256       // channels = HEADS * HD
#define HEADS 4
#define HD 64
#define NG 64        // num graphs
#define SCAN_BS 512
#define QKVS 768     // fused QKV row stride
#define LDK 40       // padded LDS k-stride (bf16 elems)

typedef __attribute__((ext_vector_type(8))) short s16x8;   // 8 x bf16 (4 VGPRs)
typedef __attribute__((ext_vector_type(4))) float f32x4;

static __device__ __forceinline__ float bf2f(unsigned short u) {
  return (float)__builtin_bit_cast(__bf16, u);
}

// ---------------- CSR build (by dst) ----------------
__global__ void hist_kernel(const int* __restrict__ dst, int* __restrict__ deg, int E) {
  int e = blockIdx.x * blockDim.x + threadIdx.x;
  if (e < E) atomicAdd(&deg[dst[e]], 1);
}

__global__ void scan1_kernel(const int* __restrict__ deg, int* __restrict__ exc,
                             int* __restrict__ partial, int n) {
  __shared__ int s[SCAN_BS];
  int t = threadIdx.x;
  int g = blockIdx.x * SCAN_BS + t;
  int v = (g < n) ? deg[g] : 0;
  s[t] = v;
  __syncthreads();
  for (int off = 1; off < SCAN_BS; off <<= 1) {
    int add = (t >= off) ? s[t - off] : 0;
    __syncthreads();
    s[t] += add;
    __syncthreads();
  }
  if (g < n) exc[g] = s[t] - v;
  if (t == SCAN_BS - 1) partial[blockIdx.x] = s[t];
}

__global__ void scan2_kernel(int* __restrict__ partial, int nb) {
  __shared__ int s[SCAN_BS];
  int t = threadIdx.x;
  int v = (t < nb) ? partial[t] : 0;
  s[t] = v;
  __syncthreads();
  for (int off = 1; off < SCAN_BS; off <<= 1) {
    int add = (t >= off) ? s[t - off] : 0;
    __syncthreads();
    s[t] += add;
    __syncthreads();
  }
  if (t < nb) partial[t] = s[t] - v;
}

__global__ void scan3_kernel(const int* __restrict__ exc, const int* __restrict__ partial,
                             int* __restrict__ row_start, int* __restrict__ cursor,
                             int n, int E) {
  int g = blockIdx.x * blockDim.x + threadIdx.x;
  if (g < n) {
    int v = exc[g] + partial[g / SCAN_BS];
    row_start[g] = v;
    cursor[g] = v;
  }
  if (g == n) row_start[n] = E;
}

__global__ void scatter_kernel(const int* __restrict__ srcArr, const int* __restrict__ dstArr,
                               int* __restrict__ cursor, int* __restrict__ csr_src,
                               int* __restrict__ csr_dst, int E) {
  int e = blockIdx.x * blockDim.x + threadIdx.x;
  if (e < E) {
    int d = dstArr[e];
    int p = atomicAdd(&cursor[d], 1);
    csr_src[p] = srcArr[e];
    csr_dst[p] = d;
  }
}

// ---------------- weight prep: transpose + concat + bf16 hi/lo split ----------------
__global__ void wprep_kernel(const float* __restrict__ Wq, const float* __restrict__ Wk,
                             const float* __restrict__ Wv, const float* __restrict__ bq,
                             const float* __restrict__ bk, const float* __restrict__ bv,
                             unsigned short* __restrict__ Bth, unsigned short* __restrict__ Btl,
                             float* __restrict__ biascat, int L) {
  int idx = blockIdx.x * 256 + threadIdx.x;
  int total = L * QKVS * CC;
  if (idx >= total) return;
  int k = idx & 255;
  int n = (idx >> 8) % QKVS;
  int l = idx / (QKVS * CC);
  int part = n >> 8;
  int nn = n & 255;
  const float* W = part == 0 ? Wq : (part == 1 ? Wk : Wv);
  float v = W[((long)l * CC + k) * CC + nn];
  __bf16 h = (__bf16)v;
  Bth[idx] = __builtin_bit_cast(unsigned short, h);
  Btl[idx] = __builtin_bit_cast(unsigned short, (__bf16)(v - (float)h));
  if (k == 0) {
    const float* bb = part == 0 ? bq : (part == 1 ? bk : bv);
    biascat[l * QKVS + n] = bb[l * CC + nn];
  }
}

// ---------------- activation split: fp32 -> bf16 hi + lo (layer-0 input only) ------
__global__ void split_kernel(const float* __restrict__ in, unsigned short* __restrict__ hi,
                             unsigned short* __restrict__ lo, int n4) {
  int i = blockIdx.x * 256 + threadIdx.x;
  if (i >= n4) return;
  float4 v = ((const float4*)in)[i];
  __bf16 h0 = (__bf16)v.x, h1 = (__bf16)v.y, h2 = (__bf16)v.z, h3 = (__bf16)v.w;
  ushort4 hv = make_ushort4(__builtin_bit_cast(unsigned short, h0),
                            __builtin_bit_cast(unsigned short, h1),
                            __builtin_bit_cast(unsigned short, h2),
                            __builtin_bit_cast(unsigned short, h3));
  ushort4 lv = make_ushort4(__builtin_bit_cast(unsigned short, (__bf16)(v.x - (float)h0)),
                            __builtin_bit_cast(unsigned short, (__bf16)(v.y - (float)h1)),
                            __builtin_bit_cast(unsigned short, (__bf16)(v.z - (float)h2)),
                            __builtin_bit_cast(unsigned short, (__bf16)(v.w - (float)h3)));
  ((ushort4*)hi)[i] = hv;
  ((ushort4*)lo)[i] = lv;
}

// ---------------- fused QKV GEMM via split-bf16 MFMA ----------------
__global__ __launch_bounds__(256) void qkv_gemm(const unsigned short* __restrict__ Ah,
                                                const unsigned short* __restrict__ Al,
                                                const unsigned short* __restrict__ Bh,
                                                const unsigned short* __restrict__ Bl,
                                                const float* __restrict__ biascat,
                                                float* __restrict__ C, int M) {
  __shared__ unsigned short As_h[128 * LDK], As_l[128 * LDK];
  __shared__ unsigned short Bs_h[128 * LDK], Bs_l[128 * LDK];
  int t = threadIdx.x;
  int bm = blockIdx.x, bn = blockIdx.y;
  int lane = t & 63, wave = t >> 6;
  int mo = (wave >> 1) * 64, no = (wave & 1) * 64;
  int col_l = lane & 15, q = lane >> 4;

  f32x4 acc[4][4];
#pragma unroll
  for (int i = 0; i < 4; ++i)
#pragma unroll
    for (int j = 0; j < 4; ++j) acc[i][j] = (f32x4)0.f;

  int sr = t >> 1;
  int sh = (t & 1) * 16;
  long arow = (long)bm * 128 + sr;
  bool aval = arow < M;
  const unsigned short* agh = Ah + arow * CC + sh;
  const unsigned short* agl = Al + arow * CC + sh;
  const unsigned short* bgh = Bh + ((long)bn * 128 + sr) * CC + sh;
  const unsigned short* bgl = Bl + ((long)bn * 128 + sr) * CC + sh;
  uint4 zz = make_uint4(0, 0, 0, 0);

  for (int kt = 0; kt < CC; kt += 32) {
    uint4 ah0 = zz, ah1 = zz, al0 = zz, al1 = zz;
    if (aval) {
      ah0 = *(const uint4*)(agh + kt);
      ah1 = *(const uint4*)(agh + kt + 8);
      al0 = *(const uint4*)(agl + kt);
      al1 = *(const uint4*)(agl + kt + 8);
    }
    uint4 bh0 = *(const uint4*)(bgh + kt);
    uint4 bh1 = *(const uint4*)(bgh + kt + 8);
    uint4 bl0 = *(const uint4*)(bgl + kt);
    uint4 bl1 = *(const uint4*)(bgl + kt + 8);
    __syncthreads();
    *(uint4*)&As_h[sr * LDK + sh] = ah0;
    *(uint4*)&As_h[sr * LDK + sh + 8] = ah1;
    *(uint4*)&As_l[sr * LDK + sh] = al0;
    *(uint4*)&As_l[sr * LDK + sh + 8] = al1;
    *(uint4*)&Bs_h[sr * LDK + sh] = bh0;
    *(uint4*)&Bs_h[sr * LDK + sh + 8] = bh1;
    *(uint4*)&Bs_l[sr * LDK + sh] = bl0;
    *(uint4*)&Bs_l[sr * LDK + sh + 8] = bl1;
    __syncthreads();

    s16x8 afh[4], afl[4], bfh[4], bfl[4];
#pragma unroll
    for (int i = 0; i < 4; ++i) {
      int am = mo + i * 16 + col_l;
      afh[i] = *(const s16x8*)&As_h[am * LDK + q * 8];
      afl[i] = *(const s16x8*)&As_l[am * LDK + q * 8];
      int bnn = no + i * 16 + col_l;
      bfh[i] = *(const s16x8*)&Bs_h[bnn * LDK + q * 8];
      bfl[i] = *(const s16x8*)&Bs_l[bnn * LDK + q * 8];
    }
#pragma unroll
    for (int i = 0; i < 4; ++i)
#pragma unroll
      for (int j = 0; j < 4; ++j) {
        acc[i][j] = __builtin_amdgcn_mfma_f32_16x16x32_bf16(afh[i], bfh[j], acc[i][j], 0, 0, 0);
        acc[i][j] = __builtin_amdgcn_mfma_f32_16x16x32_bf16(afh[i], bfl[j], acc[i][j], 0, 0, 0);
        acc[i][j] = __builtin_amdgcn_mfma_f32_16x16x32_bf16(afl[i], bfh[j], acc[i][j], 0, 0, 0);
      }
  }

  long rbase = (long)bm * 128 + mo;
  int cbase = bn * 128 + no;
#pragma unroll
  for (int j = 0; j < 4; ++j) {
    int col = cbase + j * 16 + col_l;
    float bias = biascat[col];
#pragma unroll
    for (int i = 0; i < 4; ++i) {
#pragma unroll
      for (int r = 0; r < 4; ++r) {
        long row = rbase + i * 16 + q * 4 + r;
        if (row < M) C[row * QKVS + col] = acc[i][j][r] + bias;
      }
    }
  }
}

// ---------------- attention phase 1: per-edge logits (4 edges/wave) ----------------
// XCD-affinity swizzle: hw assigns block b to XCD b%8 (round-robin); remap so each
// XCD owns a CONTIGUOUS 1/8 of the edge list -> Q-row reuse (dst-sorted, ~deg~16
// consecutive edges) stays in ONE XCD's L2 instead of being split across 8.
__global__ __launch_bounds__(256) void edge_logits_kernel(const float* __restrict__ qkv,
                                                          const int* __restrict__ csr_src,
                                                          const int* __restrict__ csr_dst,
                                                          float* __restrict__ logits, int E,
                                                          int cpx /* chunks per XCD */) {
  int b = blockIdx.x;
  int chunk = (b & 7) * cpx + (b >> 3);
  int wave = threadIdx.x >> 6;
  int lane = threadIdx.x & 63;
  int base = chunk * 16 + wave;
  int e0 = base, e1 = base + 4, e2 = base + 8, e3 = base + 12;
  bool v0 = e0 < E, v1 = e1 < E, v2 = e2 < E, v3 = e3 < E;
  int s0i = v0 ? csr_src[e0] : 0;
  int s1i = v1 ? csr_src[e1] : 0;
  int s2i = v2 ? csr_src[e2] : 0;
  int s3i = v3 ? csr_src[e3] : 0;
  int d0i = v0 ? csr_dst[e0] : 0;
  int d1i = v1 ? csr_dst[e1] : 0;
  int d2i = v2 ? csr_dst[e2] : 0;
  int d3i = v3 ? csr_dst[e3] : 0;
  // 8 independent 1KB-row loads in flight; lane*4 covers the full row
  const float4 q0 = *(const float4*)(qkv + (size_t)d0i * QKVS + lane * 4);
  const float4 k0 = *(const float4*)(qkv + (size_t)s0i * QKVS + 256 + lane * 4);
  const float4 q1 = *(const float4*)(qkv + (size_t)d1i * QKVS + lane * 4);
  const float4 k1 = *(const float4*)(qkv + (size_t)s1i * QKVS + 256 + lane * 4);
  const float4 q2 = *(const float4*)(qkv + (size_t)d2i * QKVS + lane * 4);
  const float4 k2 = *(const float4*)(qkv + (size_t)s2i * QKVS + 256 + lane * 4);
  const float4 q3 = *(const float4*)(qkv + (size_t)d3i * QKVS + lane * 4);
  const float4 k3 = *(const float4*)(qkv + (size_t)s3i * QKVS + 256 + lane * 4);
  float dot0 = q0.x * k0.x + q0.y * k0.y + q0.z * k0.z + q0.w * k0.w;
  float dot1 = q1.x * k1.x + q1.y * k1.y + q1.z * k1.z + q1.w * k1.w;
  float dot2 = q2.x * k2.x + q2.y * k2.y + q2.z * k2.z + q2.w * k2.w;
  float dot3 = q3.x * k3.x + q3.y * k3.y + q3.z * k3.z + q3.w * k3.w;
#pragma unroll
  for (int off = 1; off < 16; off <<= 1) {
    dot0 += __shfl_xor(dot0, off, 64);
    dot1 += __shfl_xor(dot1, off, 64);
    dot2 += __shfl_xor(dot2, off, 64);
    dot3 += __shfl_xor(dot3, off, 64);
  }
  if ((lane & 15) == 0) {
    int h = lane >> 4;
    float* plane = logits + (size_t)h * E;
    if (v0) plane[e0] = dot0 * 0.125f;
    if (v1) plane[e1] = dot1 * 0.125f;
    if (v2) plane[e2] = dot2 * 0.125f;
    if (v3) plane[e3] = dot3 * 0.125f;
  }
}

// ---------------- attention phase 2+3 fused: softmax + V aggregation + ReLU -------
// block = node (XCD-swizzled), wave = head. Wave computes (m, 1/z) over its logits
// segment with lane-parallel coalesced reads, then the 8x-unrolled V gather.
__global__ __launch_bounds__(256) void aggregate_kernel(const float* __restrict__ qkv,
                                                        const float* __restrict__ logits,
                                                        const int* __restrict__ row_start,
                                                        const int* __restrict__ csr_src,
                                                        unsigned short* __restrict__ h_hi,
                                                        unsigned short* __restrict__ h_lo,
                                                        int N, int E,
                                                        int npx /* nodes per XCD */) {
  int b = blockIdx.x;
  int node = (b & 7) * npx + (b >> 3);
  if (node >= N) return;
  int wave = threadIdx.x >> 6;
  int lane = threadIdx.x & 63;
  int s0 = row_start[node], s1 = row_start[node + 1];
  float h = 0.f;
  if (s1 > s0) {
    const float* lp = logits + (size_t)wave * E;
    // lane-parallel max
    float m = -1e30f;
    for (int i = s0 + lane; i < s1; i += 64) m = fmaxf(m, lp[i]);
#pragma unroll
    for (int off = 32; off; off >>= 1) m = fmaxf(m, __shfl_xor(m, off, 64));
    // lane-parallel exp-sum
    float z = 0.f;
    for (int i = s0 + lane; i < s1; i += 64) z += __expf(lp[i] - m);
#pragma unroll
    for (int off = 32; off; off >>= 1) z += __shfl_xor(z, off, 64);
    float rz = 1.f / (z + 1e-16f);

    const float* vbase = qkv + 512 + threadIdx.x;
    float acc = 0.f;
    int i = s0;
    for (; i + 8 <= s1; i += 8) {
      int ix[8];
      float lg[8], vv[8];
#pragma unroll
      for (int u = 0; u < 8; ++u) ix[u] = csr_src[i + u];
#pragma unroll
      for (int u = 0; u < 8; ++u) lg[u] = lp[i + u];
#pragma unroll
      for (int u = 0; u < 8; ++u) vv[u] = vbase[(size_t)ix[u] * QKVS];
#pragma unroll
      for (int u = 0; u < 8; ++u) acc = fmaf(__expf(lg[u] - m) * rz, vv[u], acc);
    }
    for (; i + 4 <= s1; i += 4) {
      int a = csr_src[i], b2 = csr_src[i + 1], c = csr_src[i + 2], d = csr_src[i + 3];
      float la = lp[i], lb = lp[i + 1], lc = lp[i + 2], ld = lp[i + 3];
      float va = vbase[(size_t)a * QKVS];
      float vb = vbase[(size_t)b2 * QKVS];
      float vc = vbase[(size_t)c * QKVS];
      float vd = vbase[(size_t)d * QKVS];
      acc = fmaf(__expf(la - m) * rz, va, acc);
      acc = fmaf(__expf(lb - m) * rz, vb, acc);
      acc = fmaf(__expf(lc - m) * rz, vc, acc);
      acc = fmaf(__expf(ld - m) * rz, vd, acc);
    }
    for (; i < s1; ++i) {
      int a = csr_src[i];
      acc = fmaf(__expf(lp[i] - m) * rz, vbase[(size_t)a * QKVS], acc);
    }
    h = fmaxf(acc, 0.f);
  }
  __bf16 hi = (__bf16)h;
  size_t idx = (size_t)node * CC + threadIdx.x;
  h_hi[idx] = __builtin_bit_cast(unsigned short, hi);
  h_lo[idx] = __builtin_bit_cast(unsigned short, (__bf16)(h - (float)hi));
}

// ---------------- pool: parallel segment-sum with atomics (batch sorted) ----------------
__global__ void pool_kernel(const unsigned short* __restrict__ h_hi,
                            const unsigned short* __restrict__ h_lo,
                            const int* __restrict__ batch,
                            float* __restrict__ gpool, int N) {
  int c = threadIdx.x;
  int n0 = blockIdx.x * 64;
  int n1 = min(n0 + 64, N);
  int cur = batch[n0];
  float acc = 0.f;
  for (int n = n0; n < n1; ++n) {
    int g = batch[n];
    if (g != cur) {
      atomicAdd(&gpool[cur * CC + c], acc);
      acc = 0.f;
      cur = g;
    }
    size_t idx = (size_t)n * CC + c;
    acc += bf2f(h_hi[idx]) + bf2f(h_lo[idx]);
  }
  atomicAdd(&gpool[cur * CC + c], acc);
}

// ---------------- MLP head ----------------
__global__ void head_kernel(const float* __restrict__ gpool, const float* __restrict__ W1,
                            const float* __restrict__ b1, const float* __restrict__ W2,
                            const float* __restrict__ b2, float* __restrict__ out) {
  __shared__ float hid[64];
  int g = blockIdx.x, t = threadIdx.x;
  float acc = b1[t];
  for (int i = 0; i < CC; ++i) acc = fmaf(gpool[g * CC + i], W1[i * 64 + t], acc);
  hid[t] = fmaxf(acc, 0.f);
  __syncthreads();
  if (t < 16) {
    float o = b2[t];
    for (int i = 0; i < 64; ++i) o = fmaf(hid[i], W2[i * 16 + t], o);
    out[g * 16 + t] = o;
  }
}

extern "C" void kernel_launch(void* const* d_in, const int* in_sizes, int n_in,
                              void* d_out, int out_size, void* d_ws, size_t ws_size,
                              hipStream_t stream) {
  const float* x  = (const float*)d_in[0];
  const int* ei   = (const int*)d_in[1];
  const int* batch = (const int*)d_in[2];
  const float* Wq = (const float*)d_in[3];
  const float* bq = (const float*)d_in[4];
  const float* Wk = (const float*)d_in[5];
  const float* bk = (const float*)d_in[6];
  const float* Wv = (const float*)d_in[7];
  const float* bv = (const float*)d_in[8];
  const float* W1 = (const float*)d_in[9];
  const float* b1 = (const float*)d_in[10];
  const float* W2 = (const float*)d_in[11];
  const float* b2 = (const float*)d_in[12];
  float* out = (float*)d_out;

  int N = in_sizes[0] / CC;
  int E = in_sizes[1] / 2;
  int L = in_sizes[3] / (CC * CC);
  const int* src = ei;
  const int* dst = ei + E;

  // workspace budget: keep total < 256 MB (R3 crashed at ~278 MB)
  size_t off = 0;
  auto alloc = [&](size_t bytes) -> void* {
    void* p = (char*)d_ws + off;
    off += (bytes + 255) & ~(size_t)255;
    return p;
  };
  float* qkv = (float*)alloc((size_t)N * QKVS * 4);                   // 153.6 MB
  unsigned short* h_hi = (unsigned short*)alloc((size_t)N * CC * 2);  // 25.6 MB
  unsigned short* h_lo = (unsigned short*)alloc((size_t)N * CC * 2);  // 25.6 MB
  unsigned short* Bth = (unsigned short*)alloc((size_t)L * QKVS * CC * 2);
  unsigned short* Btl = (unsigned short*)alloc((size_t)L * QKVS * CC * 2);
  float* biascat = (float*)alloc((size_t)L * QKVS * 4);
  int* deg = (int*)alloc((size_t)N * 4);
  int* exc = (int*)alloc((size_t)N * 4);
  int* partial = (int*)alloc(SCAN_BS * 4);
  int* row_start = (int*)alloc((size_t)(N + 1) * 4);
  int* cursor = (int*)alloc((size_t)N * 4);
  int* csr_src = (int*)alloc((size_t)E * 4);
  int* csr_dst = (int*)alloc((size_t)E * 4);
  float* wbuf = (float*)alloc((size_t)E * HEADS * 4);                 // 12.8 MB
  float* gpool = (float*)alloc((size_t)NG * CC * 4);
  // total ~= 227 MB

  // CSR by dst
  hipMemsetAsync(deg, 0, (size_t)N * 4, stream);
  int eb = (E + 255) / 256;
  hist_kernel<<<eb, 256, 0, stream>>>(dst, deg, E);
  int nb = (N + SCAN_BS - 1) / SCAN_BS;
  scan1_kernel<<<nb, SCAN_BS, 0, stream>>>(deg, exc, partial, N);
  scan2_kernel<<<1, SCAN_BS, 0, stream>>>(partial, nb);
  scan3_kernel<<<(N + 1 + 255) / 256, 256, 0, stream>>>(exc, partial, row_start, cursor, N, E);
  scatter_kernel<<<eb, 256, 0, stream>>>(src, dst, cursor, csr_src, csr_dst, E);

  // weight prep (transpose + concat + hi/lo split)
  int wtot = L * QKVS * CC;
  wprep_kernel<<<(wtot + 255) / 256, 256, 0, stream>>>(Wq, Wk, Wv, bq, bk, bv,
                                                       Bth, Btl, biascat, L);

  // layer-0 input split
  int n4 = N * CC / 4;
  split_kernel<<<(n4 + 255) / 256, 256, 0, stream>>>(x, h_hi, h_lo, n4);

  // layers
  dim3 gemmGrid((N + 127) / 128, QKVS / 128);
  int ewb = (E + 15) / 16;            // 16 edges per block
  int cpx = (ewb + 7) / 8;            // chunks per XCD
  int ewb_pad = cpx * 8;              // padded grid: swizzle stays injective
  int npx = (N + 7) / 8;              // nodes per XCD
  int ngrid = npx * 8;
  for (int l = 0; l < L; ++l) {
    qkv_gemm<<<gemmGrid, 256, 0, stream>>>(h_hi, h_lo,
                                           Bth + (size_t)l * QKVS * CC,
                                           Btl + (size_t)l * QKVS * CC,
                                           biascat + (size_t)l * QKVS, qkv, N);
    edge_logits_kernel<<<ewb_pad, 256, 0, stream>>>(qkv, csr_src, csr_dst, wbuf, E, cpx);
    aggregate_kernel<<<ngrid, 256, 0, stream>>>(qkv, wbuf, row_start, csr_src,
                                                h_hi, h_lo, N, E, npx);
  }

  // pool + head
  hipMemsetAsync(gpool, 0, (size_t)NG * CC * 4, stream);
  pool_kernel<<<(N + 63) / 64, 256, 0, stream>>>(h_hi, h_lo, batch, gpool, N);
  head_kernel<<<NG, 64, 0, stream>>>(gpool, W1, b1, W2, b2, out);
}

// Round 10
// 1259.344 us; speedup vs baseline: 1.1818x; 1.0274x over previous
//
#include <hip/hip_runtime.h>
#include <math.h>

#define CC 256       // channels = HEADS * HD
#define HEADS 4
#define HD 64
#define NG 64        // num graphs
#define SCAN_BS 512
#define QKVS 768     // fused QKV row stride
#define LDK 40       // padded LDS k-stride (bf16 elems)

typedef __attribute__((ext_vector_type(8))) short s16x8;   // 8 x bf16 (4 VGPRs)
typedef __attribute__((ext_vector_type(4))) float f32x4;

static __device__ __forceinline__ float bf2f(unsigned short u) {
  return (float)__builtin_bit_cast(__bf16, u);
}

// ---------------- CSR build (by dst) ----------------
__global__ void hist_kernel(const int* __restrict__ dst, int* __restrict__ deg, int E) {
  int e = blockIdx.x * blockDim.x + threadIdx.x;
  if (e < E) atomicAdd(&deg[dst[e]], 1);
}

__global__ void scan1_kernel(const int* __restrict__ deg, int* __restrict__ exc,
                             int* __restrict__ partial, int n) {
  __shared__ int s[SCAN_BS];
  int t = threadIdx.x;
  int g = blockIdx.x * SCAN_BS + t;
  int v = (g < n) ? deg[g] : 0;
  s[t] = v;
  __syncthreads();
  for (int off = 1; off < SCAN_BS; off <<= 1) {
    int add = (t >= off) ? s[t - off] : 0;
    __syncthreads();
    s[t] += add;
    __syncthreads();
  }
  if (g < n) exc[g] = s[t] - v;
  if (t == SCAN_BS - 1) partial[blockIdx.x] = s[t];
}

__global__ void scan2_kernel(int* __restrict__ partial, int nb) {
  __shared__ int s[SCAN_BS];
  int t = threadIdx.x;
  int v = (t < nb) ? partial[t] : 0;
  s[t] = v;
  __syncthreads();
  for (int off = 1; off < SCAN_BS; off <<= 1) {
    int add = (t >= off) ? s[t - off] : 0;
    __syncthreads();
    s[t] += add;
    __syncthreads();
  }
  if (t < nb) partial[t] = s[t] - v;
}

__global__ void scan3_kernel(const int* __restrict__ exc, const int* __restrict__ partial,
                             int* __restrict__ row_start, int* __restrict__ cursor,
                             int n, int E) {
  int g = blockIdx.x * blockDim.x + threadIdx.x;
  if (g < n) {
    int v = exc[g] + partial[g / SCAN_BS];
    row_start[g] = v;
    cursor[g] = v;
  }
  if (g == n) row_start[n] = E;
}

__global__ void scatter_kernel(const int* __restrict__ srcArr, const int* __restrict__ dstArr,
                               int* __restrict__ cursor, int* __restrict__ csr_src, int E) {
  int e = blockIdx.x * blockDim.x + threadIdx.x;
  if (e < E) {
    int d = dstArr[e];
    int p = atomicAdd(&cursor[d], 1);
    csr_src[p] = srcArr[e];
  }
}

// ---------------- weight prep: transpose + concat + bf16 hi/lo split ----------------
__global__ void wprep_kernel(const float* __restrict__ Wq, const float* __restrict__ Wk,
                             const float* __restrict__ Wv, const float* __restrict__ bq,
                             const float* __restrict__ bk, const float* __restrict__ bv,
                             unsigned short* __restrict__ Bth, unsigned short* __restrict__ Btl,
                             float* __restrict__ biascat, int L) {
  int idx = blockIdx.x * 256 + threadIdx.x;
  int total = L * QKVS * CC;
  if (idx >= total) return;
  int k = idx & 255;
  int n = (idx >> 8) % QKVS;
  int l = idx / (QKVS * CC);
  int part = n >> 8;
  int nn = n & 255;
  const float* W = part == 0 ? Wq : (part == 1 ? Wk : Wv);
  float v = W[((long)l * CC + k) * CC + nn];
  __bf16 h = (__bf16)v;
  Bth[idx] = __builtin_bit_cast(unsigned short, h);
  Btl[idx] = __builtin_bit_cast(unsigned short, (__bf16)(v - (float)h));
  if (k == 0) {
    const float* bb = part == 0 ? bq : (part == 1 ? bk : bv);
    biascat[l * QKVS + n] = bb[l * CC + nn];
  }
}

// ---------------- activation split: fp32 -> bf16 hi + lo (layer-0 input only) ------
__global__ void split_kernel(const float* __restrict__ in, unsigned short* __restrict__ hi,
                             unsigned short* __restrict__ lo, int n4) {
  int i = blockIdx.x * 256 + threadIdx.x;
  if (i >= n4) return;
  float4 v = ((const float4*)in)[i];
  __bf16 h0 = (__bf16)v.x, h1 = (__bf16)v.y, h2 = (__bf16)v.z, h3 = (__bf16)v.w;
  ushort4 hv = make_ushort4(__builtin_bit_cast(unsigned short, h0),
                            __builtin_bit_cast(unsigned short, h1),
                            __builtin_bit_cast(unsigned short, h2),
                            __builtin_bit_cast(unsigned short, h3));
  ushort4 lv = make_ushort4(__builtin_bit_cast(unsigned short, (__bf16)(v.x - (float)h0)),
                            __builtin_bit_cast(unsigned short, (__bf16)(v.y - (float)h1)),
                            __builtin_bit_cast(unsigned short, (__bf16)(v.z - (float)h2)),
                            __builtin_bit_cast(unsigned short, (__bf16)(v.w - (float)h3)));
  ((ushort4*)hi)[i] = hv;
  ((ushort4*)lo)[i] = lv;
}

// ---------------- fused QKV GEMM via split-bf16 MFMA ----------------
__global__ __launch_bounds__(256) void qkv_gemm(const unsigned short* __restrict__ Ah,
                                                const unsigned short* __restrict__ Al,
                                                const unsigned short* __restrict__ Bh,
                                                const unsigned short* __restrict__ Bl,
                                                const float* __restrict__ biascat,
                                                float* __restrict__ C, int M) {
  __shared__ unsigned short As_h[128 * LDK], As_l[128 * LDK];
  __shared__ unsigned short Bs_h[128 * LDK], Bs_l[128 * LDK];
  int t = threadIdx.x;
  int bm = blockIdx.x, bn = blockIdx.y;
  int lane = t & 63, wave = t >> 6;
  int mo = (wave >> 1) * 64, no = (wave & 1) * 64;
  int col_l = lane & 15, q = lane >> 4;

  f32x4 acc[4][4];
#pragma unroll
  for (int i = 0; i < 4; ++i)
#pragma unroll
    for (int j = 0; j < 4; ++j) acc[i][j] = (f32x4)0.f;

  int sr = t >> 1;
  int sh = (t & 1) * 16;
  long arow = (long)bm * 128 + sr;
  bool aval = arow < M;
  const unsigned short* agh = Ah + arow * CC + sh;
  const unsigned short* agl = Al + arow * CC + sh;
  const unsigned short* bgh = Bh + ((long)bn * 128 + sr) * CC + sh;
  const unsigned short* bgl = Bl + ((long)bn * 128 + sr) * CC + sh;
  uint4 zz = make_uint4(0, 0, 0, 0);

  for (int kt = 0; kt < CC; kt += 32) {
    uint4 ah0 = zz, ah1 = zz, al0 = zz, al1 = zz;
    if (aval) {
      ah0 = *(const uint4*)(agh + kt);
      ah1 = *(const uint4*)(agh + kt + 8);
      al0 = *(const uint4*)(agl + kt);
      al1 = *(const uint4*)(agl + kt + 8);
    }
    uint4 bh0 = *(const uint4*)(bgh + kt);
    uint4 bh1 = *(const uint4*)(bgh + kt + 8);
    uint4 bl0 = *(const uint4*)(bgl + kt);
    uint4 bl1 = *(const uint4*)(bgl + kt + 8);
    __syncthreads();
    *(uint4*)&As_h[sr * LDK + sh] = ah0;
    *(uint4*)&As_h[sr * LDK + sh + 8] = ah1;
    *(uint4*)&As_l[sr * LDK + sh] = al0;
    *(uint4*)&As_l[sr * LDK + sh + 8] = al1;
    *(uint4*)&Bs_h[sr * LDK + sh] = bh0;
    *(uint4*)&Bs_h[sr * LDK + sh + 8] = bh1;
    *(uint4*)&Bs_l[sr * LDK + sh] = bl0;
    *(uint4*)&Bs_l[sr * LDK + sh + 8] = bl1;
    __syncthreads();

    s16x8 afh[4], afl[4], bfh[4], bfl[4];
#pragma unroll
    for (int i = 0; i < 4; ++i) {
      int am = mo + i * 16 + col_l;
      afh[i] = *(const s16x8*)&As_h[am * LDK + q * 8];
      afl[i] = *(const s16x8*)&As_l[am * LDK + q * 8];
      int bnn = no + i * 16 + col_l;
      bfh[i] = *(const s16x8*)&Bs_h[bnn * LDK + q * 8];
      bfl[i] = *(const s16x8*)&Bs_l[bnn * LDK + q * 8];
    }
#pragma unroll
    for (int i = 0; i < 4; ++i)
#pragma unroll
      for (int j = 0; j < 4; ++j) {
        acc[i][j] = __builtin_amdgcn_mfma_f32_16x16x32_bf16(afh[i], bfh[j], acc[i][j], 0, 0, 0);
        acc[i][j] = __builtin_amdgcn_mfma_f32_16x16x32_bf16(afh[i], bfl[j], acc[i][j], 0, 0, 0);
        acc[i][j] = __builtin_amdgcn_mfma_f32_16x16x32_bf16(afl[i], bfh[j], acc[i][j], 0, 0, 0);
      }
  }

  long rbase = (long)bm * 128 + mo;
  int cbase = bn * 128 + no;
#pragma unroll
  for (int j = 0; j < 4; ++j) {
    int col = cbase + j * 16 + col_l;
    float bias = biascat[col];
#pragma unroll
    for (int i = 0; i < 4; ++i) {
#pragma unroll
      for (int r = 0; r < 4; ++r) {
        long row = rbase + i * 16 + q * 4 + r;
        if (row < M) C[row * QKVS + col] = acc[i][j][r] + bias;
      }
    }
  }
}

// ---------------- fused attention: logits + softmax + V-aggregate + ReLU ----------
// block = node (XCD-swizzled). lane = (head=lane>>4, dim4=lane&15) so ONE wave
// computes all 4 heads for an edge via a 4-step 16-lane dot-reduce (R1 layout).
// K and V of an edge are loaded TOGETHER (2KB of one qkv row, single cache visit);
// V is held in registers from that load. Online softmax rescales once per 4-edge
// chunk. The node's 4 waves split the edge list; partials merge through LDS.
__global__ __launch_bounds__(256) void attn_fused_kernel(const float* __restrict__ qkv,
                                                         const int* __restrict__ row_start,
                                                         const int* __restrict__ csr_src,
                                                         unsigned short* __restrict__ h_hi,
                                                         unsigned short* __restrict__ h_lo,
                                                         int N, int npx) {
  __shared__ float sm_m[4][64];
  __shared__ float sm_z[4][64];
  __shared__ f32x4 sm_a[4][64];
  int b = blockIdx.x;
  int node = (b & 7) * npx + (b >> 3);
  if (node >= N) return;
  int wave = threadIdx.x >> 6;
  int lane = threadIdx.x & 63;
  int s0 = row_start[node], s1 = row_start[node + 1];

  // Q row: lane covers channels lane*4..+3 (head lane>>4)
  const f32x4 q4 = *(const f32x4*)(qkv + (size_t)node * QKVS + lane * 4);

  float m = -1e30f, z = 0.f;
  f32x4 acc = (f32x4)0.f;

  // wave handles 4-edge chunks at stride 16
  for (int base = s0 + 4 * wave; base < s1; base += 16) {
    int cnt = min(4, s1 - base);
    f32x4 kk[4], vv[4];
    float lg[4];
#pragma unroll
    for (int u = 0; u < 4; ++u) {
      if (u < cnt) {
        int s = csr_src[base + u];
        const float* row = qkv + (size_t)s * QKVS;
        kk[u] = *(const f32x4*)(row + 256 + lane * 4);   // K
        vv[u] = *(const f32x4*)(row + 512 + lane * 4);   // V (same 2KB region)
      }
    }
#pragma unroll
    for (int u = 0; u < 4; ++u) {
      if (u < cnt) {
        float d = q4.x * kk[u].x + q4.y * kk[u].y + q4.z * kk[u].z + q4.w * kk[u].w;
#pragma unroll
        for (int off = 1; off < 16; off <<= 1) d += __shfl_xor(d, off, 64);
        lg[u] = d * 0.125f;        // per-head value in each 16-lane group
      }
    }
    float cm = lg[0];
#pragma unroll
    for (int u = 1; u < 4; ++u)
      if (u < cnt) cm = fmaxf(cm, lg[u]);
    float mn = fmaxf(m, cm);
    float sc = __expf(m - mn);     // first chunk: exp(-huge) = 0
    z *= sc;
    acc *= sc;
    m = mn;
#pragma unroll
    for (int u = 0; u < 4; ++u) {
      if (u < cnt) {
        float e = __expf(lg[u] - m);
        z += e;
        acc += e * vv[u];
      }
    }
  }

  sm_m[wave][lane] = m;
  sm_z[wave][lane] = z;
  sm_a[wave][lane] = acc;
  __syncthreads();

  if (wave == 0) {
    float mstar = sm_m[0][lane];
#pragma unroll
    for (int w = 1; w < 4; ++w) mstar = fmaxf(mstar, sm_m[w][lane]);
    float zstar = 0.f;
    f32x4 astar = (f32x4)0.f;
#pragma unroll
    for (int w = 0; w < 4; ++w) {
      float s = __expf(sm_m[w][lane] - mstar);
      zstar += sm_z[w][lane] * s;
      astar += sm_a[w][lane] * s;
    }
    float rz = 1.f / (zstar + 1e-16f);
    ushort4 ohi, olo;
    float o0 = fmaxf(astar.x * rz, 0.f);
    float o1 = fmaxf(astar.y * rz, 0.f);
    float o2 = fmaxf(astar.z * rz, 0.f);
    float o3 = fmaxf(astar.w * rz, 0.f);
    __bf16 h0 = (__bf16)o0, h1 = (__bf16)o1, h2 = (__bf16)o2, h3 = (__bf16)o3;
    ohi = make_ushort4(__builtin_bit_cast(unsigned short, h0),
                       __builtin_bit_cast(unsigned short, h1),
                       __builtin_bit_cast(unsigned short, h2),
                       __builtin_bit_cast(unsigned short, h3));
    olo = make_ushort4(__builtin_bit_cast(unsigned short, (__bf16)(o0 - (float)h0)),
                       __builtin_bit_cast(unsigned short, (__bf16)(o1 - (float)h1)),
                       __builtin_bit_cast(unsigned short, (__bf16)(o2 - (float)h2)),
                       __builtin_bit_cast(unsigned short, (__bf16)(o3 - (float)h3)));
    size_t idx = (size_t)node * CC + lane * 4;
    *(ushort4*)(h_hi + idx) = ohi;
    *(ushort4*)(h_lo + idx) = olo;
  }
}

// ---------------- pool: parallel segment-sum with atomics (batch sorted) ----------------
__global__ void pool_kernel(const unsigned short* __restrict__ h_hi,
                            const unsigned short* __restrict__ h_lo,
                            const int* __restrict__ batch,
                            float* __restrict__ gpool, int N) {
  int c = threadIdx.x;
  int n0 = blockIdx.x * 64;
  int n1 = min(n0 + 64, N);
  int cur = batch[n0];
  float acc = 0.f;
  for (int n = n0; n < n1; ++n) {
    int g = batch[n];
    if (g != cur) {
      atomicAdd(&gpool[cur * CC + c], acc);
      acc = 0.f;
      cur = g;
    }
    size_t idx = (size_t)n * CC + c;
    acc += bf2f(h_hi[idx]) + bf2f(h_lo[idx]);
  }
  atomicAdd(&gpool[cur * CC + c], acc);
}

// ---------------- MLP head ----------------
__global__ void head_kernel(const float* __restrict__ gpool, const float* __restrict__ W1,
                            const float* __restrict__ b1, const float* __restrict__ W2,
                            const float* __restrict__ b2, float* __restrict__ out) {
  __shared__ float hid[64];
  int g = blockIdx.x, t = threadIdx.x;
  float acc = b1[t];
  for (int i = 0; i < CC; ++i) acc = fmaf(gpool[g * CC + i], W1[i * 64 + t], acc);
  hid[t] = fmaxf(acc, 0.f);
  __syncthreads();
  if (t < 16) {
    float o = b2[t];
    for (int i = 0; i < 64; ++i) o = fmaf(hid[i], W2[i * 16 + t], o);
    out[g * 16 + t] = o;
  }
}

extern "C" void kernel_launch(void* const* d_in, const int* in_sizes, int n_in,
                              void* d_out, int out_size, void* d_ws, size_t ws_size,
                              hipStream_t stream) {
  const float* x  = (const float*)d_in[0];
  const int* ei   = (const int*)d_in[1];
  const int* batch = (const int*)d_in[2];
  const float* Wq = (const float*)d_in[3];
  const float* bq = (const float*)d_in[4];
  const float* Wk = (const float*)d_in[5];
  const float* bk = (const float*)d_in[6];
  const float* Wv = (const float*)d_in[7];
  const float* bv = (const float*)d_in[8];
  const float* W1 = (const float*)d_in[9];
  const float* b1 = (const float*)d_in[10];
  const float* W2 = (const float*)d_in[11];
  const float* b2 = (const float*)d_in[12];
  float* out = (float*)d_out;

  int N = in_sizes[0] / CC;
  int E = in_sizes[1] / 2;
  int L = in_sizes[3] / (CC * CC);
  const int* src = ei;
  const int* dst = ei + E;

  // workspace budget: keep total < 256 MB (R3 crashed at ~278 MB)
  size_t off = 0;
  auto alloc = [&](size_t bytes) -> void* {
    void* p = (char*)d_ws + off;
    off += (bytes + 255) & ~(size_t)255;
    return p;
  };
  float* qkv = (float*)alloc((size_t)N * QKVS * 4);                   // 153.6 MB
  unsigned short* h_hi = (unsigned short*)alloc((size_t)N * CC * 2);  // 25.6 MB
  unsigned short* h_lo = (unsigned short*)alloc((size_t)N * CC * 2);  // 25.6 MB
  unsigned short* Bth = (unsigned short*)alloc((size_t)L * QKVS * CC * 2);
  unsigned short* Btl = (unsigned short*)alloc((size_t)L * QKVS * CC * 2);
  float* biascat = (float*)alloc((size_t)L * QKVS * 4);
  int* deg = (int*)alloc((size_t)N * 4);
  int* exc = (int*)alloc((size_t)N * 4);
  int* partial = (int*)alloc(SCAN_BS * 4);
  int* row_start = (int*)alloc((size_t)(N + 1) * 4);
  int* cursor = (int*)alloc((size_t)N * 4);
  int* csr_src = (int*)alloc((size_t)E * 4);
  float* gpool = (float*)alloc((size_t)NG * CC * 4);
  // total ~= 211 MB

  // CSR by dst
  hipMemsetAsync(deg, 0, (size_t)N * 4, stream);
  int eb = (E + 255) / 256;
  hist_kernel<<<eb, 256, 0, stream>>>(dst, deg, E);
  int nb = (N + SCAN_BS - 1) / SCAN_BS;
  scan1_kernel<<<nb, SCAN_BS, 0, stream>>>(deg, exc, partial, N);
  scan2_kernel<<<1, SCAN_BS, 0, stream>>>(partial, nb);
  scan3_kernel<<<(N + 1 + 255) / 256, 256, 0, stream>>>(exc, partial, row_start, cursor, N, E);
  scatter_kernel<<<eb, 256, 0, stream>>>(src, dst, cursor, csr_src, E);

  // weight prep (transpose + concat + hi/lo split)
  int wtot = L * QKVS * CC;
  wprep_kernel<<<(wtot + 255) / 256, 256, 0, stream>>>(Wq, Wk, Wv, bq, bk, bv,
                                                       Bth, Btl, biascat, L);

  // layer-0 input split
  int n4 = N * CC / 4;
  split_kernel<<<(n4 + 255) / 256, 256, 0, stream>>>(x, h_hi, h_lo, n4);

  // layers
  dim3 gemmGrid((N + 127) / 128, QKVS / 128);
  int npx = (N + 7) / 8;              // nodes per XCD
  int ngrid = npx * 8;
  for (int l = 0; l < L; ++l) {
    qkv_gemm<<<gemmGrid, 256, 0, stream>>>(h_hi, h_lo,
                                           Bth + (size_t)l * QKVS * CC,
                                           Btl + (size_t)l * QKVS * CC,
                                           biascat + (size_t)l * QKVS, qkv, N);
    attn_fused_kernel<<<ngrid, 256, 0, stream>>>(qkv, row_start, csr_src,
                                                 h_hi, h_lo, N, npx);
  }

  // pool + head
  hipMemsetAsync(gpool, 0, (size_t)NG * CC * 4, stream);
  pool_kernel<<<(N + 63) / 64, 256, 0, stream>>>(h_hi, h_lo, batch, gpool, N);
  head_kernel<<<NG, 64, 0, stream>>>(gpool, W1, b1, W2, b2, out);
}